// Round 1
// baseline (896.586 us; speedup 1.0000x reference)
//
#include <hip/hip_runtime.h>

#define NN 50000
#define NE 800000
#define ND 128
#define ED 64

// ---------------- workspace layout (float-element offsets) ----------------
// deg   int[NN]      @ 0
// norm  f32[NN]      @ 50176
// invd  f32[NN]      @ 100352
// sArr  f32[NN]      @ 150528
// tArr  f32[NN]      @ 200704
// F     f32[NN*64]   @ 250880   (ends at 3450880 elems = 13,803,520 bytes)
// G (f32[NN*128]) lives in d_out (zeroed at launch, overwritten by epilogue).

__global__ void k_deg(const int* __restrict__ dst, int* __restrict__ deg) {
    int i = blockIdx.x * blockDim.x + threadIdx.x;
    if (i < NE) atomicAdd(&deg[dst[i]], 1);
}

__global__ void k_norm(const int* __restrict__ deg, float* __restrict__ norm,
                       float* __restrict__ invd) {
    int n = blockIdx.x * blockDim.x + threadIdx.x;
    if (n < NN) {
        float d = (float)(deg[n] + 1);
        norm[n] = rsqrtf(d);
        invd[n] = 1.0f / d;
    }
}

// One wave (64 lanes) per edge.
__global__ void k_scatter(const int* __restrict__ src, const int* __restrict__ dst,
                          const float* __restrict__ nfeat, const float* __restrict__ efeat,
                          const float* __restrict__ norm,
                          float* __restrict__ F, float* G,
                          float* __restrict__ sArr, float* __restrict__ tArr) {
    int e = (blockIdx.x * blockDim.x + threadIdx.x) >> 6;
    int lane = threadIdx.x & 63;
    if (e >= NE) return;
    int s = src[e], d = dst[e];
    float ns = norm[s], nd = norm[d];
    float w = ns * nd;
    // F[d] += w * efeat[e]  (64 channels, one per lane)
    atomicAdd(&F[d * ED + lane], w * efeat[(size_t)e * ED + lane]);
    // G[d] += ns * nfeat[s] (128 channels, two per lane)
    atomicAdd(&G[d * ND + lane],      ns * nfeat[(size_t)s * ND + lane]);
    atomicAdd(&G[d * ND + lane + 64], ns * nfeat[(size_t)s * ND + lane + 64]);
    if (lane == 0) {
        atomicAdd(&sArr[d], w);
        atomicAdd(&tArr[d], ns);
    }
}

// Final fused GEMM: out[n][j] = sum_{k<128} A[n][k]*Wn[k][j]
//                             + sum_{k<64}  F[n][k]*We[k][j]
//                             + (norm*t + invd)*bn[j] + s*be[j] + invd*resid[j]
// where A[n][k] = norm[n]*G[n][k] + invd[n]*nfeat[n][k].
// Block tile: 64 nodes x 128 channels, K=192 in chunks of 32.
#define TM 64
#define KC 32

__global__ __launch_bounds__(256) void k_gemm(
        const float* __restrict__ nfeat, const float* __restrict__ Wn,
        const float* __restrict__ bn, const float* __restrict__ We,
        const float* __restrict__ be, const float* __restrict__ resid,
        const float* __restrict__ norm, const float* __restrict__ invd,
        const float* __restrict__ sArr, const float* __restrict__ tArr,
        const float* __restrict__ F, const float* G, float* out) {
    __shared__ float As[KC][TM + 4];   // transposed A chunk, padded
    __shared__ float Bs[KC][ND + 4];   // B chunk, padded

    const int tid = threadIdx.x;
    const int nodeBase = blockIdx.x * TM;

    const int wv = tid >> 6, lane = tid & 63;
    const int wm = wv & 1, wn = wv >> 1;
    const int ln = lane & 7, lj = lane >> 3;
    const int rowN = wm * 32 + ln * 4;   // node offset within tile (4 nodes)
    const int colJ = wn * 64 + lj * 8;   // channel base (8 channels)

    float acc[4][8];
#pragma unroll
    for (int r = 0; r < 4; ++r)
#pragma unroll
        for (int c = 0; c < 8; ++c) acc[r][c] = 0.0f;

    for (int kb = 0; kb < 6; ++kb) {
        __syncthreads();   // protect LDS reuse from previous chunk's compute
        // ---- stage A chunk (64 nodes x 32 k), transposed into As ----
#pragma unroll
        for (int i = 0; i < 2; ++i) {
            int idx = tid + 256 * i;       // 0..511
            int node = idx >> 3;           // 0..63
            int kl = (idx & 7) * 4;        // 0,4,..,28
            int gn = nodeBase + node;
            float ax = 0.f, ay = 0.f, az = 0.f, aw = 0.f;
            if (gn < NN) {
                if (kb < 4) {
                    int k = kb * 32 + kl;
                    float4 g4 = *(const float4*)&G[(size_t)gn * ND + k];
                    float4 n4 = *(const float4*)&nfeat[(size_t)gn * ND + k];
                    float nm = norm[gn], iv = invd[gn];
                    ax = nm * g4.x + iv * n4.x;
                    ay = nm * g4.y + iv * n4.y;
                    az = nm * g4.z + iv * n4.z;
                    aw = nm * g4.w + iv * n4.w;
                } else {
                    int k = (kb - 4) * 32 + kl;
                    float4 f4 = *(const float4*)&F[(size_t)gn * ED + k];
                    ax = f4.x; ay = f4.y; az = f4.z; aw = f4.w;
                }
            }
            As[kl + 0][node] = ax;
            As[kl + 1][node] = ay;
            As[kl + 2][node] = az;
            As[kl + 3][node] = aw;
        }
        // ---- stage B chunk (32 k x 128 j) ----
#pragma unroll
        for (int i = 0; i < 4; ++i) {
            int idx = tid + 256 * i;       // 0..1023
            int kl = idx >> 5;             // 0..31
            int j = (idx & 31) * 4;
            int k = kb * 32 + kl;
            float4 b4 = (k < ND) ? *(const float4*)&Wn[(size_t)k * ND + j]
                                 : *(const float4*)&We[(size_t)(k - ND) * ND + j];
            *(float4*)&Bs[kl][j] = b4;
        }
        __syncthreads();
        // ---- compute ----
#pragma unroll
        for (int kl = 0; kl < KC; ++kl) {
            float4 a4 = *(const float4*)&As[kl][rowN];
            float4 b0 = *(const float4*)&Bs[kl][colJ];
            float4 b1 = *(const float4*)&Bs[kl][colJ + 4];
            float av[4] = {a4.x, a4.y, a4.z, a4.w};
            float bv[8] = {b0.x, b0.y, b0.z, b0.w, b1.x, b1.y, b1.z, b1.w};
#pragma unroll
            for (int r = 0; r < 4; ++r)
#pragma unroll
                for (int c = 0; c < 8; ++c) acc[r][c] += av[r] * bv[c];
        }
    }

    // ---- epilogue: bias + residual, write out ----
#pragma unroll
    for (int r = 0; r < 4; ++r) {
        int gn = nodeBase + rowN + r;
        if (gn >= NN) continue;
        float nm = norm[gn], iv = invd[gn];
        float tv = tArr[gn], sv = sArr[gn];
        float cb = nm * tv + iv;
        float o[8];
#pragma unroll
        for (int c = 0; c < 8; ++c) {
            int j = colJ + c;
            o[c] = acc[r][c] + cb * bn[j] + sv * be[j] + iv * resid[j];
        }
        float4* op = (float4*)&out[(size_t)gn * ND + colJ];
        op[0] = make_float4(o[0], o[1], o[2], o[3]);
        op[1] = make_float4(o[4], o[5], o[6], o[7]);
    }
}

extern "C" void kernel_launch(void* const* d_in, const int* in_sizes, int n_in,
                              void* d_out, int out_size, void* d_ws, size_t ws_size,
                              hipStream_t stream) {
    const int*   src   = (const int*)  d_in[0];
    const int*   dst   = (const int*)  d_in[1];
    const float* nfeat = (const float*)d_in[2];
    const float* efeat = (const float*)d_in[3];
    const float* Wn    = (const float*)d_in[4];
    const float* bn    = (const float*)d_in[5];
    const float* We    = (const float*)d_in[6];
    const float* be    = (const float*)d_in[7];
    const float* resid = (const float*)d_in[8];
    float* out = (float*)d_out;
    float* ws  = (float*)d_ws;

    int*   deg  = (int*)d_ws;
    float* norm = ws + 50176;
    float* invd = ws + 100352;
    float* sArr = ws + 150528;
    float* tArr = ws + 200704;
    float* F    = ws + 250880;
    float* G    = out;   // reuse d_out as the 128-dim scatter accumulator

    // zero: deg/s/t/F region + G (=d_out); harness poisons both with 0xAA
    hipMemsetAsync(d_ws, 0, (size_t)3450880 * 4, stream);
    hipMemsetAsync(d_out, 0, (size_t)NN * ND * 4, stream);

    k_deg<<<(NE + 255) / 256, 256, 0, stream>>>(dst, deg);
    k_norm<<<(NN + 255) / 256, 256, 0, stream>>>(deg, norm, invd);
    k_scatter<<<(NE * 64) / 256, 256, 0, stream>>>(src, dst, nfeat, efeat, norm,
                                                   F, G, sArr, tArr);
    k_gemm<<<(NN + TM - 1) / TM, 256, 0, stream>>>(nfeat, Wn, bn, We, be, resid,
                                                   norm, invd, sArr, tArr, F, G, out);
}

// Round 2
// 586.712 us; speedup vs baseline: 1.5282x; 1.5282x over previous
//
#include <hip/hip_runtime.h>

#define NN 50000
#define NE 800000
#define ND 128
#define ED 64
#define NB1 196   // ceil(NN/256)

// ---------------- workspace layout (element offsets, 4B elems) ----------------
// deg    int[50176]   @ 0          (zeroed)
// cursor int[50176]   @ 50176      (zeroed)
// offs   int[50176]   @ 100352
// bsums  int[256]     @ 150528
// bsum2  int[256]     @ 150784
// norm   f32[50176]   @ 151040
// invd   f32[50176]   @ 201216
// cbArr  f32[50176]   @ 251392
// sArr   f32[50176]   @ 301568
// eidx   int[800000]  @ 351744
// F      f32[3.2M]    @ 1151744    -> total 4,351,744 elems = 16.6 MB
// A128 (f32[NN*128]) lives in d_out: gather writes it, GEMM reads+overwrites.

__global__ void k_deg(const int* __restrict__ dst, int* __restrict__ deg) {
    int i = blockIdx.x * blockDim.x + threadIdx.x;
    if (i < NE) atomicAdd(&deg[dst[i]], 1);
}

__global__ void k_norm(const int* __restrict__ deg, float* __restrict__ norm,
                       float* __restrict__ invd) {
    int n = blockIdx.x * blockDim.x + threadIdx.x;
    if (n < NN) {
        float d = (float)(deg[n] + 1);
        norm[n] = rsqrtf(d);
        invd[n] = 1.0f / d;
    }
}

__global__ void k_scan1(const int* __restrict__ deg, int* __restrict__ offs,
                        int* __restrict__ bsums) {
    __shared__ int sh[256];
    int i = blockIdx.x * 256 + threadIdx.x;
    int v = (i < NN) ? deg[i] : 0;
    sh[threadIdx.x] = v;
    __syncthreads();
    int x = v;
#pragma unroll
    for (int o = 1; o < 256; o <<= 1) {
        int y = (threadIdx.x >= o) ? sh[threadIdx.x - o] : 0;
        __syncthreads();
        x += y;
        sh[threadIdx.x] = x;
        __syncthreads();
    }
    if (i < NN) offs[i] = x - v;           // exclusive
    if (threadIdx.x == 255) bsums[blockIdx.x] = x;
}

__global__ void k_scan2(const int* __restrict__ bsums, int* __restrict__ bsum2) {
    __shared__ int sh[256];
    int t = threadIdx.x;
    int v = (t < NB1) ? bsums[t] : 0;
    sh[t] = v;
    __syncthreads();
    int x = v;
#pragma unroll
    for (int o = 1; o < 256; o <<= 1) {
        int y = (t >= o) ? sh[t - o] : 0;
        __syncthreads();
        x += y;
        sh[t] = x;
        __syncthreads();
    }
    bsum2[t] = x - v;                       // exclusive
}

__global__ void k_scan3(int* __restrict__ offs, const int* __restrict__ bsum2) {
    int i = blockIdx.x * 256 + threadIdx.x;
    if (i < NN) offs[i] += bsum2[blockIdx.x];
}

__global__ void k_fill(const int* __restrict__ dst, const int* __restrict__ offs,
                       int* __restrict__ cursor, int* __restrict__ eidx) {
    int e = blockIdx.x * blockDim.x + threadIdx.x;
    if (e < NE) {
        int d = dst[e];
        int pos = offs[d] + atomicAdd(&cursor[d], 1);
        eidx[pos] = e;
    }
}

// One wave per dst node: gather incoming edges, no float atomics.
// Writes A128 row (into d_out), F row, and epilogue scalars cb/s.
__global__ __launch_bounds__(256) void k_gather(
        const int* __restrict__ src, const int* __restrict__ eidx,
        const int* __restrict__ offs, const int* __restrict__ deg,
        const float* __restrict__ nfeat, const float* __restrict__ efeat,
        const float* __restrict__ norm, const float* __restrict__ invd,
        float* __restrict__ A128, float* __restrict__ F,
        float* __restrict__ cbArr, float* __restrict__ sArr) {
    int n = blockIdx.x * 4 + (threadIdx.x >> 6);
    int lane = threadIdx.x & 63;
    if (n >= NN) return;
    int beg = offs[n], cnt = deg[n];
    float nd = norm[n];
    float accF = 0.f, g0 = 0.f, g1 = 0.f, sA = 0.f, tA = 0.f;
    for (int i = 0; i < cnt; ++i) {
        int e = eidx[beg + i];
        int s = src[e];
        float ns = norm[s];
        sA += ns * nd;
        tA += ns;
        accF += (ns * nd) * efeat[(size_t)e * ED + lane];
        g0 += ns * nfeat[(size_t)s * ND + lane];
        g1 += ns * nfeat[(size_t)s * ND + lane + 64];
    }
    float iv = invd[n];
    A128[(size_t)n * ND + lane]      = nd * g0 + iv * nfeat[(size_t)n * ND + lane];
    A128[(size_t)n * ND + lane + 64] = nd * g1 + iv * nfeat[(size_t)n * ND + lane + 64];
    F[(size_t)n * ED + lane] = accF;
    if (lane == 0) {
        cbArr[n] = nd * tA + iv;
        sArr[n] = sA;
    }
}

// out[n][j] = sum_{k<128} A128[n][k]*Wn[k][j] + sum_{k<64} F[n][k]*We[k][j]
//           + cb[n]*bn[j] + s[n]*be[j] + invd[n]*resid[j]
#define TM 64
#define KC 32

__global__ __launch_bounds__(256) void k_gemm(
        const float* __restrict__ Wn, const float* __restrict__ bn,
        const float* __restrict__ We, const float* __restrict__ be,
        const float* __restrict__ resid, const float* __restrict__ invd,
        const float* __restrict__ cbArr, const float* __restrict__ sArr,
        const float* __restrict__ F, const float* A128, float* out) {
    __shared__ float As[KC][TM + 4];
    __shared__ float Bs[KC][ND + 4];

    const int tid = threadIdx.x;
    const int nodeBase = blockIdx.x * TM;

    const int wv = tid >> 6, lane = tid & 63;
    const int wm = wv & 1, wn = wv >> 1;
    const int ln = lane & 7, lj = lane >> 3;
    const int rowN = wm * 32 + ln * 4;
    const int colJ = wn * 64 + lj * 8;

    float acc[4][8];
#pragma unroll
    for (int r = 0; r < 4; ++r)
#pragma unroll
        for (int c = 0; c < 8; ++c) acc[r][c] = 0.0f;

    for (int kb = 0; kb < 6; ++kb) {
        __syncthreads();
#pragma unroll
        for (int i = 0; i < 2; ++i) {
            int idx = tid + 256 * i;
            int node = idx >> 3;
            int kl = (idx & 7) * 4;
            int gn = nodeBase + node;
            float ax = 0.f, ay = 0.f, az = 0.f, aw = 0.f;
            if (gn < NN) {
                if (kb < 4) {
                    float4 g4 = *(const float4*)&A128[(size_t)gn * ND + kb * 32 + kl];
                    ax = g4.x; ay = g4.y; az = g4.z; aw = g4.w;
                } else {
                    float4 f4 = *(const float4*)&F[(size_t)gn * ED + (kb - 4) * 32 + kl];
                    ax = f4.x; ay = f4.y; az = f4.z; aw = f4.w;
                }
            }
            As[kl + 0][node] = ax;
            As[kl + 1][node] = ay;
            As[kl + 2][node] = az;
            As[kl + 3][node] = aw;
        }
#pragma unroll
        for (int i = 0; i < 4; ++i) {
            int idx = tid + 256 * i;
            int kl = idx >> 5;
            int j = (idx & 31) * 4;
            int k = kb * 32 + kl;
            float4 b4 = (k < ND) ? *(const float4*)&Wn[(size_t)k * ND + j]
                                 : *(const float4*)&We[(size_t)(k - ND) * ND + j];
            *(float4*)&Bs[kl][j] = b4;
        }
        __syncthreads();
#pragma unroll
        for (int kl = 0; kl < KC; ++kl) {
            float4 a4 = *(const float4*)&As[kl][rowN];
            float4 b0 = *(const float4*)&Bs[kl][colJ];
            float4 b1 = *(const float4*)&Bs[kl][colJ + 4];
            float av[4] = {a4.x, a4.y, a4.z, a4.w};
            float bv[8] = {b0.x, b0.y, b0.z, b0.w, b1.x, b1.y, b1.z, b1.w};
#pragma unroll
            for (int r = 0; r < 4; ++r)
#pragma unroll
                for (int c = 0; c < 8; ++c) acc[r][c] += av[r] * bv[c];
        }
    }

#pragma unroll
    for (int r = 0; r < 4; ++r) {
        int gn = nodeBase + rowN + r;
        if (gn >= NN) continue;
        float cb = cbArr[gn], sv = sArr[gn], iv = invd[gn];
        float o[8];
#pragma unroll
        for (int c = 0; c < 8; ++c) {
            int j = colJ + c;
            o[c] = acc[r][c] + cb * bn[j] + sv * be[j] + iv * resid[j];
        }
        float4* op = (float4*)&out[(size_t)gn * ND + colJ];
        op[0] = make_float4(o[0], o[1], o[2], o[3]);
        op[1] = make_float4(o[4], o[5], o[6], o[7]);
    }
}

extern "C" void kernel_launch(void* const* d_in, const int* in_sizes, int n_in,
                              void* d_out, int out_size, void* d_ws, size_t ws_size,
                              hipStream_t stream) {
    const int*   src   = (const int*)  d_in[0];
    const int*   dst   = (const int*)  d_in[1];
    const float* nfeat = (const float*)d_in[2];
    const float* efeat = (const float*)d_in[3];
    const float* Wn    = (const float*)d_in[4];
    const float* bn    = (const float*)d_in[5];
    const float* We    = (const float*)d_in[6];
    const float* be    = (const float*)d_in[7];
    const float* resid = (const float*)d_in[8];
    float* out = (float*)d_out;
    float* ws  = (float*)d_ws;

    int*   deg    = (int*)d_ws;
    int*   cursor = (int*)d_ws + 50176;
    int*   offs   = (int*)d_ws + 100352;
    int*   bsums  = (int*)d_ws + 150528;
    int*   bsum2  = (int*)d_ws + 150784;
    float* norm   = ws + 151040;
    float* invd   = ws + 201216;
    float* cbArr  = ws + 251392;
    float* sArr   = ws + 301568;
    int*   eidx   = (int*)d_ws + 351744;
    float* F      = ws + 1151744;
    float* A128   = out;   // gather writes A into d_out; gemm reads + overwrites

    // zero deg + cursor only
    hipMemsetAsync(d_ws, 0, (size_t)100352 * 4, stream);

    k_deg  <<<(NE + 255) / 256, 256, 0, stream>>>(dst, deg);
    k_norm <<<NB1, 256, 0, stream>>>(deg, norm, invd);
    k_scan1<<<NB1, 256, 0, stream>>>(deg, offs, bsums);
    k_scan2<<<1, 256, 0, stream>>>(bsums, bsum2);
    k_scan3<<<NB1, 256, 0, stream>>>(offs, bsum2);
    k_fill <<<(NE + 255) / 256, 256, 0, stream>>>(dst, offs, cursor, eidx);
    k_gather<<<12500, 256, 0, stream>>>(src, eidx, offs, deg, nfeat, efeat,
                                        norm, invd, A128, F, cbArr, sArr);
    k_gemm <<<(NN + TM - 1) / TM, 256, 0, stream>>>(Wn, bn, We, be, resid, invd,
                                                    cbArr, sArr, F, A128, out);
}

// Round 3
// 485.720 us; speedup vs baseline: 1.8459x; 1.2079x over previous
//
#include <hip/hip_runtime.h>

#define NN 50000
#define NE 800000
#define ND 128
#define ED 64
#define NB1 196   // ceil(NN/256)

// ---------------- workspace layout (element offsets, 4B elems) ----------------
// deg    int[50176]    @ 0          (zeroed)
// cursor int[50176]    @ 50176     (zeroed)
// offs   int[50176]    @ 100352
// bsums  int[256]      @ 150528
// bsum2  int[256]      @ 150784
// norm   f32[50176]    @ 151040
// invd   f32[50176]    @ 201216
// cbArr  f32[50176]    @ 251392
// sArr   f32[50176]    @ 301568
// eArr   int[800000]   @ 351744
// swArr  int2[800000]  @ 1154048   (byte offset 4,616,192 — 8B aligned)
// F      f32[3.2M]     @ 2754048   -> total 5,954,048 elems = 22.7 MB
// A128 (f32[NN*128]) lives in d_out: gather writes it, GEMM reads+overwrites.

__global__ void k_deg(const int* __restrict__ dst, int* __restrict__ deg) {
    int i = blockIdx.x * blockDim.x + threadIdx.x;
    if (i < NE) atomicAdd(&deg[dst[i]], 1);
}

__global__ void k_scan1(const int* __restrict__ deg, int* __restrict__ offs,
                        int* __restrict__ bsums) {
    __shared__ int sh[256];
    int i = blockIdx.x * 256 + threadIdx.x;
    int v = (i < NN) ? deg[i] : 0;
    sh[threadIdx.x] = v;
    __syncthreads();
    int x = v;
#pragma unroll
    for (int o = 1; o < 256; o <<= 1) {
        int y = (threadIdx.x >= o) ? sh[threadIdx.x - o] : 0;
        __syncthreads();
        x += y;
        sh[threadIdx.x] = x;
        __syncthreads();
    }
    if (i < NN) offs[i] = x - v;           // exclusive
    if (threadIdx.x == 255) bsums[blockIdx.x] = x;
}

__global__ void k_scan2(const int* __restrict__ bsums, int* __restrict__ bsum2) {
    __shared__ int sh[256];
    int t = threadIdx.x;
    int v = (t < NB1) ? bsums[t] : 0;
    sh[t] = v;
    __syncthreads();
    int x = v;
#pragma unroll
    for (int o = 1; o < 256; o <<= 1) {
        int y = (t >= o) ? sh[t - o] : 0;
        __syncthreads();
        x += y;
        sh[t] = x;
        __syncthreads();
    }
    bsum2[t] = x - v;                       // exclusive
}

// offs finalize + norm/invd (merged elementwise pass)
__global__ void k_scan3(int* __restrict__ offs, const int* __restrict__ bsum2,
                        const int* __restrict__ deg, float* __restrict__ norm,
                        float* __restrict__ invd) {
    int i = blockIdx.x * 256 + threadIdx.x;
    if (i < NN) {
        offs[i] += bsum2[blockIdx.x];
        float d = (float)(deg[i] + 1);
        norm[i] = rsqrtf(d);
        invd[i] = 1.0f / d;
    }
}

// CSR fill, pre-resolving the src indirection: store (src, norm[src]) + e.
__global__ void k_fill(const int* __restrict__ dst, const int* __restrict__ src,
                       const float* __restrict__ norm, const int* __restrict__ offs,
                       int* __restrict__ cursor, int2* __restrict__ swArr,
                       int* __restrict__ eArr) {
    int e = blockIdx.x * blockDim.x + threadIdx.x;
    if (e < NE) {
        int d = dst[e], s = src[e];
        int pos = offs[d] + atomicAdd(&cursor[d], 1);
        swArr[pos] = make_int2(s, __float_as_int(norm[s]));
        eArr[pos] = e;
    }
}

// One wave per dst node. Lane l loads edge-record l of the segment (coalesced),
// inner loop broadcasts record j via shfl -> all feature loads are independent.
__global__ __launch_bounds__(256) void k_gather(
        const int2* __restrict__ swArr, const int* __restrict__ eArr,
        const int* __restrict__ offs, const int* __restrict__ deg,
        const float* __restrict__ nfeat, const float* __restrict__ efeat,
        const float* __restrict__ norm, const float* __restrict__ invd,
        float* __restrict__ A128, float* __restrict__ F,
        float* __restrict__ cbArr, float* __restrict__ sArr) {
    int n = blockIdx.x * 4 + (threadIdx.x >> 6);
    int lane = threadIdx.x & 63;
    if (n >= NN) return;   // never true at this grid; keeps whole waves uniform
    int beg = offs[n], cnt = deg[n];
    float nd = norm[n];
    float accF = 0.f, g0 = 0.f, g1 = 0.f, tA = 0.f;

    for (int base = 0; base < cnt; base += 64) {
        int m = cnt - base; if (m > 64) m = 64;
        int2 sw = make_int2(0, 0);
        int ee = 0;
        if (lane < m) {
            sw = swArr[beg + base + lane];
            ee = eArr[beg + base + lane];
        }
        float nsl = __int_as_float(sw.y);   // 0.0f for invalid lanes
        tA += nsl;
        int mp = (m + 3) & ~3;              // pad: invalid j has ns==0, s==e==0
        for (int j = 0; j < mp; j += 4) {
#pragma unroll
            for (int u = 0; u < 4; ++u) {
                int jj = j + u;
                int s   = __shfl(sw.x, jj);
                float ns = __shfl(nsl, jj);
                int e2  = __shfl(ee, jj);
                g0   += ns * nfeat[(size_t)s * ND + lane];
                g1   += ns * nfeat[(size_t)s * ND + lane + 64];
                accF += ns * efeat[(size_t)e2 * ED + lane];
            }
        }
    }
    // wave-reduce tA (sum of norm[src] over all incoming edges)
#pragma unroll
    for (int o = 32; o > 0; o >>= 1) tA += __shfl_xor(tA, o);

    float iv = invd[n];
    A128[(size_t)n * ND + lane]      = nd * g0 + iv * nfeat[(size_t)n * ND + lane];
    A128[(size_t)n * ND + lane + 64] = nd * g1 + iv * nfeat[(size_t)n * ND + lane + 64];
    F[(size_t)n * ED + lane] = nd * accF;
    if (lane == 0) {
        float sA = nd * tA;       // == sum of norm[src]*norm[dst]
        cbArr[n] = sA ? sA + iv : sA + iv;  // keep simple: cb = nd*tA + iv
        cbArr[n] = sA + iv;
        sArr[n]  = sA;
    }
}

// out[n][j] = sum_{k<128} A128[n][k]*Wn[k][j] + sum_{k<64} F[n][k]*We[k][j]
//           + cb[n]*bn[j] + s[n]*be[j] + invd[n]*resid[j]
#define TM 64
#define KC 32

__global__ __launch_bounds__(256) void k_gemm(
        const float* __restrict__ Wn, const float* __restrict__ bn,
        const float* __restrict__ We, const float* __restrict__ be,
        const float* __restrict__ resid, const float* __restrict__ invd,
        const float* __restrict__ cbArr, const float* __restrict__ sArr,
        const float* __restrict__ F, const float* A128, float* out) {
    __shared__ float As[KC][TM + 4];
    __shared__ float Bs[KC][ND + 4];

    const int tid = threadIdx.x;
    const int nodeBase = blockIdx.x * TM;

    const int wv = tid >> 6, lane = tid & 63;
    const int wm = wv & 1, wn = wv >> 1;
    const int ln = lane & 7, lj = lane >> 3;
    const int rowN = wm * 32 + ln * 4;
    const int colJ = wn * 64 + lj * 8;

    float acc[4][8];
#pragma unroll
    for (int r = 0; r < 4; ++r)
#pragma unroll
        for (int c = 0; c < 8; ++c) acc[r][c] = 0.0f;

    for (int kb = 0; kb < 6; ++kb) {
        __syncthreads();
#pragma unroll
        for (int i = 0; i < 2; ++i) {
            int idx = tid + 256 * i;
            int node = idx >> 3;
            int kl = (idx & 7) * 4;
            int gn = nodeBase + node;
            float ax = 0.f, ay = 0.f, az = 0.f, aw = 0.f;
            if (gn < NN) {
                if (kb < 4) {
                    float4 g4 = *(const float4*)&A128[(size_t)gn * ND + kb * 32 + kl];
                    ax = g4.x; ay = g4.y; az = g4.z; aw = g4.w;
                } else {
                    float4 f4 = *(const float4*)&F[(size_t)gn * ED + (kb - 4) * 32 + kl];
                    ax = f4.x; ay = f4.y; az = f4.z; aw = f4.w;
                }
            }
            As[kl + 0][node] = ax;
            As[kl + 1][node] = ay;
            As[kl + 2][node] = az;
            As[kl + 3][node] = aw;
        }
#pragma unroll
        for (int i = 0; i < 4; ++i) {
            int idx = tid + 256 * i;
            int kl = idx >> 5;
            int j = (idx & 31) * 4;
            int k = kb * 32 + kl;
            float4 b4 = (k < ND) ? *(const float4*)&Wn[(size_t)k * ND + j]
                                 : *(const float4*)&We[(size_t)(k - ND) * ND + j];
            *(float4*)&Bs[kl][j] = b4;
        }
        __syncthreads();
#pragma unroll
        for (int kl = 0; kl < KC; ++kl) {
            float4 a4 = *(const float4*)&As[kl][rowN];
            float4 b0 = *(const float4*)&Bs[kl][colJ];
            float4 b1 = *(const float4*)&Bs[kl][colJ + 4];
            float av[4] = {a4.x, a4.y, a4.z, a4.w};
            float bv[8] = {b0.x, b0.y, b0.z, b0.w, b1.x, b1.y, b1.z, b1.w};
#pragma unroll
            for (int r = 0; r < 4; ++r)
#pragma unroll
                for (int c = 0; c < 8; ++c) acc[r][c] += av[r] * bv[c];
        }
    }

#pragma unroll
    for (int r = 0; r < 4; ++r) {
        int gn = nodeBase + rowN + r;
        if (gn >= NN) continue;
        float cb = cbArr[gn], sv = sArr[gn], iv = invd[gn];
        float o[8];
#pragma unroll
        for (int c = 0; c < 8; ++c) {
            int j = colJ + c;
            o[c] = acc[r][c] + cb * bn[j] + sv * be[j] + iv * resid[j];
        }
        float4* op = (float4*)&out[(size_t)gn * ND + colJ];
        op[0] = make_float4(o[0], o[1], o[2], o[3]);
        op[1] = make_float4(o[4], o[5], o[6], o[7]);
    }
}

extern "C" void kernel_launch(void* const* d_in, const int* in_sizes, int n_in,
                              void* d_out, int out_size, void* d_ws, size_t ws_size,
                              hipStream_t stream) {
    const int*   src   = (const int*)  d_in[0];
    const int*   dst   = (const int*)  d_in[1];
    const float* nfeat = (const float*)d_in[2];
    const float* efeat = (const float*)d_in[3];
    const float* Wn    = (const float*)d_in[4];
    const float* bn    = (const float*)d_in[5];
    const float* We    = (const float*)d_in[6];
    const float* be    = (const float*)d_in[7];
    const float* resid = (const float*)d_in[8];
    float* out = (float*)d_out;
    float* ws  = (float*)d_ws;

    int*   deg    = (int*)d_ws;
    int*   cursor = (int*)d_ws + 50176;
    int*   offs   = (int*)d_ws + 100352;
    int*   bsums  = (int*)d_ws + 150528;
    int*   bsum2  = (int*)d_ws + 150784;
    float* norm   = ws + 151040;
    float* invd   = ws + 201216;
    float* cbArr  = ws + 251392;
    float* sArr   = ws + 301568;
    int*   eArr   = (int*)d_ws + 351744;
    int2*  swArr  = (int2*)((int*)d_ws + 1154048);
    float* F      = ws + 2754048;
    float* A128   = out;   // gather writes A into d_out; gemm reads + overwrites

    // zero deg + cursor only
    hipMemsetAsync(d_ws, 0, (size_t)100352 * 4, stream);

    k_deg  <<<(NE + 255) / 256, 256, 0, stream>>>(dst, deg);
    k_scan1<<<NB1, 256, 0, stream>>>(deg, offs, bsums);
    k_scan2<<<1, 256, 0, stream>>>(bsums, bsum2);
    k_scan3<<<NB1, 256, 0, stream>>>(offs, bsum2, deg, norm, invd);
    k_fill <<<(NE + 255) / 256, 256, 0, stream>>>(dst, src, norm, offs, cursor,
                                                  swArr, eArr);
    k_gather<<<12500, 256, 0, stream>>>(swArr, eArr, offs, deg, nfeat, efeat,
                                        norm, invd, A128, F, cbArr, sArr);
    k_gemm <<<(NN + TM - 1) / TM, 256, 0, stream>>>(Wn, bn, We, be, resid, invd,
                                                    cbArr, sArr, F, A128, out);
}

// Round 4
// 474.604 us; speedup vs baseline: 1.8891x; 1.0234x over previous
//
#include <hip/hip_runtime.h>

#define NN 50000
#define NE 800000
#define ND 128
#define ED 64
#define NB1 196   // ceil(NN/256)

// ---------------- workspace layout (element offsets, 4B elems) ----------------
// deg    int[50176]    @ 0         (zeroed)
// cursor int[50176]    @ 50176     (zeroed)
// offs   int[50176]    @ 100352
// bsums  int[256]      @ 150528
// bsum2  int[256]      @ 150784
// norm   f32[50176]    @ 151040
// invd   f32[50176]    @ 201216
// cbArr  f32[50176]    @ 251392
// sArr   f32[50176]    @ 301568
// swArr  int4[800000]  @ 351744    (byte 1,406,976 — 16B aligned? 1406976/16=87936 yes)
// F      f32[3.2M]     @ 3551744   -> total 6,751,744 elems = 25.8 MB
// A128 (f32[NN*128]) lives in d_out: gather writes it, GEMM reads+overwrites.

__global__ void k_deg(const int* __restrict__ dst, int* __restrict__ deg) {
    int i = blockIdx.x * blockDim.x + threadIdx.x;
    if (i < NE) atomicAdd(&deg[dst[i]], 1);
}

__global__ void k_scan1(const int* __restrict__ deg, int* __restrict__ offs,
                        int* __restrict__ bsums) {
    __shared__ int sh[256];
    int i = blockIdx.x * 256 + threadIdx.x;
    int v = (i < NN) ? deg[i] : 0;
    sh[threadIdx.x] = v;
    __syncthreads();
    int x = v;
#pragma unroll
    for (int o = 1; o < 256; o <<= 1) {
        int y = (threadIdx.x >= o) ? sh[threadIdx.x - o] : 0;
        __syncthreads();
        x += y;
        sh[threadIdx.x] = x;
        __syncthreads();
    }
    if (i < NN) offs[i] = x - v;           // exclusive
    if (threadIdx.x == 255) bsums[blockIdx.x] = x;
}

__global__ void k_scan2(const int* __restrict__ bsums, int* __restrict__ bsum2) {
    __shared__ int sh[256];
    int t = threadIdx.x;
    int v = (t < NB1) ? bsums[t] : 0;
    sh[t] = v;
    __syncthreads();
    int x = v;
#pragma unroll
    for (int o = 1; o < 256; o <<= 1) {
        int y = (t >= o) ? sh[t - o] : 0;
        __syncthreads();
        x += y;
        sh[t] = x;
        __syncthreads();
    }
    bsum2[t] = x - v;                       // exclusive
}

// offs finalize + norm/invd (merged elementwise pass)
__global__ void k_scan3(int* __restrict__ offs, const int* __restrict__ bsum2,
                        const int* __restrict__ deg, float* __restrict__ norm,
                        float* __restrict__ invd) {
    int i = blockIdx.x * 256 + threadIdx.x;
    if (i < NN) {
        offs[i] += bsum2[blockIdx.x];
        float d = (float)(deg[i] + 1);
        norm[i] = rsqrtf(d);
        invd[i] = 1.0f / d;
    }
}

// CSR fill: one scattered 16B record per edge: {src, norm[src], e, 0}.
__global__ void k_fill(const int* __restrict__ dst, const int* __restrict__ src,
                       const float* __restrict__ norm, const int* __restrict__ offs,
                       int* __restrict__ cursor, int4* __restrict__ swArr) {
    int e = blockIdx.x * blockDim.x + threadIdx.x;
    if (e < NE) {
        int d = dst[e], s = src[e];
        int pos = offs[d] + atomicAdd(&cursor[d], 1);
        swArr[pos] = make_int4(s, __float_as_int(norm[s]), e, 0);
    }
}

// One wave per dst node. Lane l loads edge-record l (one 16B coalesced load),
// inner loop broadcasts record j via shfl; 8x unroll => 24 independent loads
// in flight per wave. efeat read nontemporally (single-touch stream).
__global__ __launch_bounds__(256) void k_gather(
        const int4* __restrict__ swArr,
        const int* __restrict__ offs, const int* __restrict__ deg,
        const float* __restrict__ nfeat, const float* __restrict__ efeat,
        const float* __restrict__ norm, const float* __restrict__ invd,
        float* __restrict__ A128, float* __restrict__ F,
        float* __restrict__ cbArr, float* __restrict__ sArr) {
    int n = blockIdx.x * 4 + (threadIdx.x >> 6);
    int lane = threadIdx.x & 63;
    if (n >= NN) return;
    int beg = offs[n], cnt = deg[n];
    float nd = norm[n];
    float accF = 0.f, g0 = 0.f, g1 = 0.f, tA = 0.f;

    for (int base = 0; base < cnt; base += 64) {
        int m = cnt - base; if (m > 64) m = 64;
        int4 sw = make_int4(0, 0, 0, 0);
        if (lane < m) sw = swArr[beg + base + lane];
        float nsl = __int_as_float(sw.y);   // 0.0f for invalid lanes
        tA += nsl;
        int mp = (m + 7) & ~7;  // padded lanes: ns==0, s==e==0 (harmless hot-line loads)
        for (int j = 0; j < mp; j += 8) {
#pragma unroll
            for (int u = 0; u < 8; ++u) {
                int jj = j + u;
                int s    = __shfl(sw.x, jj);
                float ns = __shfl(nsl, jj);
                int e2   = __shfl(sw.z, jj);
                g0   += ns * nfeat[(size_t)s * ND + lane];
                g1   += ns * nfeat[(size_t)s * ND + lane + 64];
                accF += ns * __builtin_nontemporal_load(&efeat[(size_t)e2 * ED + lane]);
            }
        }
    }
    // wave-reduce tA (sum of norm[src] over all incoming edges)
#pragma unroll
    for (int o = 32; o > 0; o >>= 1) tA += __shfl_xor(tA, o);

    float iv = invd[n];
    A128[(size_t)n * ND + lane]      = nd * g0 + iv * nfeat[(size_t)n * ND + lane];
    A128[(size_t)n * ND + lane + 64] = nd * g1 + iv * nfeat[(size_t)n * ND + lane + 64];
    F[(size_t)n * ED + lane] = nd * accF;
    if (lane == 0) {
        float sA = nd * tA;       // == sum over edges of norm[src]*norm[dst]
        cbArr[n] = sA + iv;
        sArr[n]  = sA;
    }
}

// out[n][j] = sum_{k<128} A128[n][k]*Wn[k][j] + sum_{k<64} F[n][k]*We[k][j]
//           + cb[n]*bn[j] + s[n]*be[j] + invd[n]*resid[j]
#define TM 64
#define KC 32

__global__ __launch_bounds__(256) void k_gemm(
        const float* __restrict__ Wn, const float* __restrict__ bn,
        const float* __restrict__ We, const float* __restrict__ be,
        const float* __restrict__ resid, const float* __restrict__ invd,
        const float* __restrict__ cbArr, const float* __restrict__ sArr,
        const float* __restrict__ F, const float* A128, float* out) {
    __shared__ float As[KC][TM + 4];
    __shared__ float Bs[KC][ND + 4];

    const int tid = threadIdx.x;
    const int nodeBase = blockIdx.x * TM;

    const int wv = tid >> 6, lane = tid & 63;
    const int wm = wv & 1, wn = wv >> 1;
    const int ln = lane & 7, lj = lane >> 3;
    const int rowN = wm * 32 + ln * 4;
    const int colJ = wn * 64 + lj * 8;

    float acc[4][8];
#pragma unroll
    for (int r = 0; r < 4; ++r)
#pragma unroll
        for (int c = 0; c < 8; ++c) acc[r][c] = 0.0f;

    for (int kb = 0; kb < 6; ++kb) {
        __syncthreads();
#pragma unroll
        for (int i = 0; i < 2; ++i) {
            int idx = tid + 256 * i;
            int node = idx >> 3;
            int kl = (idx & 7) * 4;
            int gn = nodeBase + node;
            float ax = 0.f, ay = 0.f, az = 0.f, aw = 0.f;
            if (gn < NN) {
                if (kb < 4) {
                    float4 g4 = *(const float4*)&A128[(size_t)gn * ND + kb * 32 + kl];
                    ax = g4.x; ay = g4.y; az = g4.z; aw = g4.w;
                } else {
                    float4 f4 = *(const float4*)&F[(size_t)gn * ED + (kb - 4) * 32 + kl];
                    ax = f4.x; ay = f4.y; az = f4.z; aw = f4.w;
                }
            }
            As[kl + 0][node] = ax;
            As[kl + 1][node] = ay;
            As[kl + 2][node] = az;
            As[kl + 3][node] = aw;
        }
#pragma unroll
        for (int i = 0; i < 4; ++i) {
            int idx = tid + 256 * i;
            int kl = idx >> 5;
            int j = (idx & 31) * 4;
            int k = kb * 32 + kl;
            float4 b4 = (k < ND) ? *(const float4*)&Wn[(size_t)k * ND + j]
                                 : *(const float4*)&We[(size_t)(k - ND) * ND + j];
            *(float4*)&Bs[kl][j] = b4;
        }
        __syncthreads();
#pragma unroll
        for (int kl = 0; kl < KC; ++kl) {
            float4 a4 = *(const float4*)&As[kl][rowN];
            float4 b0 = *(const float4*)&Bs[kl][colJ];
            float4 b1 = *(const float4*)&Bs[kl][colJ + 4];
            float av[4] = {a4.x, a4.y, a4.z, a4.w};
            float bv[8] = {b0.x, b0.y, b0.z, b0.w, b1.x, b1.y, b1.z, b1.w};
#pragma unroll
            for (int r = 0; r < 4; ++r)
#pragma unroll
                for (int c = 0; c < 8; ++c) acc[r][c] += av[r] * bv[c];
        }
    }

#pragma unroll
    for (int r = 0; r < 4; ++r) {
        int gn = nodeBase + rowN + r;
        if (gn >= NN) continue;
        float cb = cbArr[gn], sv = sArr[gn], iv = invd[gn];
        float o[8];
#pragma unroll
        for (int c = 0; c < 8; ++c) {
            int j = colJ + c;
            o[c] = acc[r][c] + cb * bn[j] + sv * be[j] + iv * resid[j];
        }
        float4* op = (float4*)&out[(size_t)gn * ND + colJ];
        op[0] = make_float4(o[0], o[1], o[2], o[3]);
        op[1] = make_float4(o[4], o[5], o[6], o[7]);
    }
}

extern "C" void kernel_launch(void* const* d_in, const int* in_sizes, int n_in,
                              void* d_out, int out_size, void* d_ws, size_t ws_size,
                              hipStream_t stream) {
    const int*   src   = (const int*)  d_in[0];
    const int*   dst   = (const int*)  d_in[1];
    const float* nfeat = (const float*)d_in[2];
    const float* efeat = (const float*)d_in[3];
    const float* Wn    = (const float*)d_in[4];
    const float* bn    = (const float*)d_in[5];
    const float* We    = (const float*)d_in[6];
    const float* be    = (const float*)d_in[7];
    const float* resid = (const float*)d_in[8];
    float* out = (float*)d_out;
    float* ws  = (float*)d_ws;

    int*   deg    = (int*)d_ws;
    int*   cursor = (int*)d_ws + 50176;
    int*   offs   = (int*)d_ws + 100352;
    int*   bsums  = (int*)d_ws + 150528;
    int*   bsum2  = (int*)d_ws + 150784;
    float* norm   = ws + 151040;
    float* invd   = ws + 201216;
    float* cbArr  = ws + 251392;
    float* sArr   = ws + 301568;
    int4*  swArr  = (int4*)((int*)d_ws + 351744);
    float* F      = ws + 3551744;
    float* A128   = out;   // gather writes A into d_out; gemm reads + overwrites

    // zero deg + cursor only
    hipMemsetAsync(d_ws, 0, (size_t)100352 * 4, stream);

    k_deg  <<<(NE + 255) / 256, 256, 0, stream>>>(dst, deg);
    k_scan1<<<NB1, 256, 0, stream>>>(deg, offs, bsums);
    k_scan2<<<1, 256, 0, stream>>>(bsums, bsum2);
    k_scan3<<<NB1, 256, 0, stream>>>(offs, bsum2, deg, norm, invd);
    k_fill <<<(NE + 255) / 256, 256, 0, stream>>>(dst, src, norm, offs, cursor, swArr);
    k_gather<<<12500, 256, 0, stream>>>(swArr, offs, deg, nfeat, efeat,
                                        norm, invd, A128, F, cbArr, sArr);
    k_gemm <<<(NN + TM - 1) / TM, 256, 0, stream>>>(Wn, bn, We, be, resid, invd,
                                                    cbArr, sArr, F, A128, out);
}